// Round 2
// baseline (5416.485 us; speedup 1.0000x reference)
//
#include <hip/hip_runtime.h>
#include <hip/hip_bf16.h>

// ---------------------------------------------------------------------------
// KimiDeltaAttention — correctness-first f32 baseline (round 2: f32 output).
// Pipeline:
//  1) gemm_tile z=3 : h@{Wq,Wk,Wv} -> qb,kb,vb            [4096x2048 each]
//  2) gemm_tile z=2 : h@{Wfa,Wga}  -> tmpf,tmpg           [4096x128]
//  3) gemm_tile z=2 : {tmpf@Wfb, tmpg@Wgb} -> gb, gateb   [4096x2048]
//  4) gemm_n16      : h@Wb -> betab                       [4096x16]
//  5) conv_silu     : depthwise causal K=4 conv + SiLU, in-place on qb,kb,vb
//  6) prep_qkg      : l2norm(q)*D^-1/2, l2norm(k), g -> exp(g) (in-place)
//  7) kda_scan      : gated delta rule over T, 32 chains  -> ob
//  8) norm_gate     : RMSNorm(o)*norm_w*sigmoid(gate)     (in-place on ob)
//  9) gemm_tile     : ob@Wo -> d_out (f32 — reference output dtype)
// ---------------------------------------------------------------------------

// ---------------- tiled f32 GEMM: C[M,N] = A[M,K] @ B[K,N] ------------------
// 128x128 block tile, BK=8, 256 threads, 8x8 per-thread microtile (4+4 split).
// blockIdx.z selects one of up to 3 (A,B,C) triples (batched independent gemms).
__global__ __launch_bounds__(256) void gemm_tile(
    const float* __restrict__ A0, const float* __restrict__ A1, const float* __restrict__ A2,
    const float* __restrict__ B0, const float* __restrict__ B1, const float* __restrict__ B2,
    float* __restrict__ C0, float* __restrict__ C1, float* __restrict__ C2,
    int M, int N, int Kd)
{
    const int z = blockIdx.z;
    const float* A = (z == 0) ? A0 : (z == 1) ? A1 : A2;
    const float* B = (z == 0) ? B0 : (z == 1) ? B1 : B2;
    float* C       = (z == 0) ? C0 : (z == 1) ? C1 : C2;

    __shared__ float As[8][128];   // As[k][m]
    __shared__ float Bs[8][128];   // Bs[k][n]

    const int tid  = threadIdx.x;
    const int bm   = blockIdx.x * 128;
    const int bn   = blockIdx.y * 128;
    const int arow = tid >> 1;             // 0..127
    const int acol = (tid & 1) << 2;       // 0 or 4
    const int brow = tid >> 5;             // 0..7
    const int bcol = (tid & 31) << 2;      // 0..124
    const int ty   = tid >> 4;             // 0..15
    const int tx   = tid & 15;             // 0..15

    float acc[8][8];
#pragma unroll
    for (int i = 0; i < 8; ++i)
#pragma unroll
        for (int j = 0; j < 8; ++j) acc[i][j] = 0.f;

    const float* Ap = A + (size_t)(bm + arow) * Kd + acol;
    const float* Bp = B + (size_t)brow * N + (bn + bcol);

    for (int k0 = 0; k0 < Kd; k0 += 8) {
        float4 av = *(const float4*)(Ap + k0);
        float4 bv = *(const float4*)(Bp + (size_t)k0 * N);
        As[acol + 0][arow] = av.x;
        As[acol + 1][arow] = av.y;
        As[acol + 2][arow] = av.z;
        As[acol + 3][arow] = av.w;
        *(float4*)&Bs[brow][bcol] = bv;
        __syncthreads();
#pragma unroll
        for (int k = 0; k < 8; ++k) {
            float4 a0 = *(const float4*)&As[k][ty * 4];
            float4 a1 = *(const float4*)&As[k][64 + ty * 4];
            float4 b0 = *(const float4*)&Bs[k][tx * 4];
            float4 b1 = *(const float4*)&Bs[k][64 + tx * 4];
            float aa[8] = {a0.x, a0.y, a0.z, a0.w, a1.x, a1.y, a1.z, a1.w};
            float bb[8] = {b0.x, b0.y, b0.z, b0.w, b1.x, b1.y, b1.z, b1.w};
#pragma unroll
            for (int i = 0; i < 8; ++i)
#pragma unroll
                for (int j = 0; j < 8; ++j)
                    acc[i][j] = fmaf(aa[i], bb[j], acc[i][j]);
        }
        __syncthreads();
    }

#pragma unroll
    for (int i = 0; i < 8; ++i) {
        int r = bm + ((i >> 2) << 6) + ty * 4 + (i & 3);
#pragma unroll
        for (int jg = 0; jg < 2; ++jg) {
            int c = bn + (jg << 6) + tx * 4;
            float4 v = make_float4(acc[i][jg * 4 + 0], acc[i][jg * 4 + 1],
                                   acc[i][jg * 4 + 2], acc[i][jg * 4 + 3]);
            *(float4*)(C + (size_t)r * N + c) = v;
        }
    }
}

// ------------------- small-N GEMM for beta: N = 16 -------------------------
__global__ __launch_bounds__(256) void gemm_n16(
    const float* __restrict__ A, const float* __restrict__ B,
    float* __restrict__ C, int M, int Kd)
{
    const int tid  = threadIdx.x;
    const int n    = tid & 15;
    const int mloc = tid >> 4;  // 0..15
    const int m    = blockIdx.x * 16 + mloc;
    const float* a  = A + (size_t)m * Kd;
    const float* bn = B + n;
    float acc = 0.f;
#pragma unroll 4
    for (int k0 = 0; k0 < Kd; k0 += 8) {
        float4 a0 = *(const float4*)(a + k0);
        float4 a1 = *(const float4*)(a + k0 + 4);
        acc = fmaf(a0.x, bn[(size_t)(k0 + 0) * 16], acc);
        acc = fmaf(a0.y, bn[(size_t)(k0 + 1) * 16], acc);
        acc = fmaf(a0.z, bn[(size_t)(k0 + 2) * 16], acc);
        acc = fmaf(a0.w, bn[(size_t)(k0 + 3) * 16], acc);
        acc = fmaf(a1.x, bn[(size_t)(k0 + 4) * 16], acc);
        acc = fmaf(a1.y, bn[(size_t)(k0 + 5) * 16], acc);
        acc = fmaf(a1.z, bn[(size_t)(k0 + 6) * 16], acc);
        acc = fmaf(a1.w, bn[(size_t)(k0 + 7) * 16], acc);
    }
    C[(size_t)m * 16 + n] = acc;
}

// --------------- depthwise causal conv (K=4) + SiLU, in-place ---------------
// thread owns one (tensor, b, c) column; batched loads break the latency chain.
__global__ __launch_bounds__(256) void conv_silu(
    float* __restrict__ q, float* __restrict__ k, float* __restrict__ v,
    const float* __restrict__ wq, const float* __restrict__ wk,
    const float* __restrict__ wv)
{
    constexpr int T = 2048, C = 2048;
    const int gid   = blockIdx.x * 256 + threadIdx.x;  // 0..12287
    const int which = gid >> 12;                        // tensor 0,1,2
    const int rem   = gid & 4095;
    const int b     = rem >> 11;
    const int c     = rem & 2047;
    float* x        = (which == 0) ? q : (which == 1) ? k : v;
    const float* w  = (which == 0) ? wq : (which == 1) ? wk : wv;

    const float w0 = w[c * 4 + 0], w1 = w[c * 4 + 1];
    const float w2 = w[c * 4 + 2], w3 = w[c * 4 + 3];
    float* p = x + (size_t)b * T * C + c;
    float xm3 = 0.f, xm2 = 0.f, xm1 = 0.f;

    for (int t0 = 0; t0 < T; t0 += 16) {
        float xt[16], yo[16];
#pragma unroll
        for (int j = 0; j < 16; ++j) xt[j] = p[(size_t)(t0 + j) * C];
#pragma unroll
        for (int j = 0; j < 16; ++j) {
            float y = fmaf(xm3, w0, fmaf(xm2, w1, fmaf(xm1, w2, xt[j] * w3)));
            yo[j] = y / (1.f + __expf(-y));   // SiLU
            xm3 = xm2; xm2 = xm1; xm1 = xt[j];
        }
#pragma unroll
        for (int j = 0; j < 16; ++j) p[(size_t)(t0 + j) * C] = yo[j];
    }
}

// ------ prep: l2norm(q)*D^-0.5, l2norm(k), g -> exp(-exp(A_log)*softplus) ---
// one wave per (b,t,h) row of 128; 2 elements per lane.
__global__ __launch_bounds__(256) void prep_qkg(
    float* __restrict__ Qb, float* __restrict__ Kb, float* __restrict__ Gb,
    const float* __restrict__ A_log, const float* __restrict__ dt_bias,
    int rows)
{
    const int wave = threadIdx.x >> 6;
    const int lane = threadIdx.x & 63;
    const int row  = blockIdx.x * 4 + wave;
    if (row >= rows) return;
    const int hh = row & 15;             // row = ((b*T+t)*16 + h)
    const size_t base = (size_t)row * 128;

    float q0 = Qb[base + lane], q1 = Qb[base + 64 + lane];
    float k0 = Kb[base + lane], k1 = Kb[base + 64 + lane];
    float sq = q0 * q0 + q1 * q1;
    float sk = k0 * k0 + k1 * k1;
#pragma unroll
    for (int off = 32; off >= 1; off >>= 1) {
        sq += __shfl_xor(sq, off);
        sk += __shfl_xor(sk, off);
    }
    const float qs = rsqrtf(sq + 1e-6f) * 0.08838834764831845f;  // * D^-1/2
    const float ks = rsqrtf(sk + 1e-6f);
    Qb[base + lane] = q0 * qs; Qb[base + 64 + lane] = q1 * qs;
    Kb[base + lane] = k0 * ks; Kb[base + 64 + lane] = k1 * ks;

    const float a = __expf(A_log[hh]);
    float x0 = Gb[base + lane]      + dt_bias[hh * 128 + lane];
    float x1 = Gb[base + 64 + lane] + dt_bias[hh * 128 + 64 + lane];
    float sp0 = (x0 > 20.f) ? x0 : log1pf(__expf(x0));
    float sp1 = (x1 > 20.f) ? x1 : log1pf(__expf(x1));
    Gb[base + lane]      = __expf(-a * sp0);   // store exp(g)
    Gb[base + 64 + lane] = __expf(-a * sp1);
}

// --------------------- gated delta-rule sequential scan ---------------------
// block = (b,h); 256 threads; thread owns (dv = tid&127, dk half = tid>>7),
// 64 f32 state elements in registers. t+1 vectors prefetched into regs.
__global__ __launch_bounds__(256) void kda_scan(
    const float* __restrict__ Q, const float* __restrict__ Kk,
    const float* __restrict__ V, const float* __restrict__ EG,
    const float* __restrict__ Braw, float* __restrict__ O)
{
    constexpr int T = 2048, H = 16, D = 128;
    const int bh  = blockIdx.x;
    const int b   = bh >> 4;
    const int hh  = bh & 15;
    const int tid = threadIdx.x;
    const int dv  = tid & 127;
    const int kbase = (tid >> 7) << 6;   // 0 or 64

    __shared__ float q_s[128], k_s[128], v_s[128], eg_s[128];
    __shared__ float part[256], part2[256];

    float s[64];
#pragma unroll
    for (int i = 0; i < 64; ++i) s[i] = 0.f;

    const size_t base = ((size_t)b * T * H + hh) * D;
    const float* qp = Q + base;
    const float* kp = Kk + base;
    const float* vp = V + base;
    const float* ep = EG + base;
    const float* bp = Braw + (size_t)b * T * H + hh;
    float* op = O + base;

    // prefetch t = 0
    float r0, r1;
    if (tid < 128) { r0 = qp[dv]; r1 = kp[dv]; }
    else           { r0 = vp[dv]; r1 = ep[dv]; }
    float betaraw = bp[0];

    for (int t = 0; t < T; ++t) {
        if (tid < 128) { q_s[dv] = r0; k_s[dv] = r1; }
        else           { v_s[dv] = r0; eg_s[dv] = r1; }
        __syncthreads();

        // prefetch t+1 (hidden under compute)
        if (t + 1 < T) {
            const size_t off = (size_t)(t + 1) * (H * D);
            if (tid < 128) { r0 = qp[off + dv]; r1 = kp[off + dv]; }
            else           { r0 = vp[off + dv]; r1 = ep[off + dv]; }
        }
        const float beta = 1.f / (1.f + __expf(-betaraw));
        if (t + 1 < T) betaraw = bp[(size_t)(t + 1) * H];

        // decay + k^T S partial
        float kpart = 0.f;
#pragma unroll
        for (int i = 0; i < 64; ++i) {
            float sv = s[i] * eg_s[kbase + i];
            s[i] = sv;
            kpart = fmaf(k_s[kbase + i], sv, kpart);
        }
        part[tid] = kpart;
        __syncthreads();

        const float kS    = part[dv] + part[dv | 128];
        const float delta = beta * (v_s[dv] - kS);

        // rank-1 update + q^T S partial
        float opart = 0.f;
#pragma unroll
        for (int i = 0; i < 64; ++i) {
            float sv = fmaf(k_s[kbase + i], delta, s[i]);
            s[i] = sv;
            opart = fmaf(q_s[kbase + i], sv, opart);
        }
        part2[tid] = opart;
        __syncthreads();

        if (tid < 128) op[(size_t)t * (H * D) + dv] = part2[dv] + part2[dv | 128];
        __syncthreads();
    }
}

// --------------- gated RMSNorm: o = rms(o)*norm_w*sigmoid(gate) -------------
__global__ __launch_bounds__(256) void norm_gate(
    float* __restrict__ O, const float* __restrict__ Gate,
    const float* __restrict__ norm_w, int rows)
{
    const int wave = threadIdx.x >> 6;
    const int lane = threadIdx.x & 63;
    const int row  = blockIdx.x * 4 + wave;
    if (row >= rows) return;
    const size_t base = (size_t)row * 128;

    float o0 = O[base + lane], o1 = O[base + 64 + lane];
    float ss = o0 * o0 + o1 * o1;
#pragma unroll
    for (int off = 32; off >= 1; off >>= 1) ss += __shfl_xor(ss, off);
    const float scale = rsqrtf(ss * (1.f / 128.f) + 1e-6f);

    const float g0 = Gate[base + lane], g1 = Gate[base + 64 + lane];
    o0 = o0 * scale * norm_w[lane]      * (1.f / (1.f + __expf(-g0)));
    o1 = o1 * scale * norm_w[64 + lane] * (1.f / (1.f + __expf(-g1)));
    O[base + lane] = o0;
    O[base + 64 + lane] = o1;
}

// ---------------------------------------------------------------------------
extern "C" void kernel_launch(void* const* d_in, const int* in_sizes, int n_in,
                              void* d_out, int out_size, void* d_ws, size_t ws_size,
                              hipStream_t stream)
{
    const float* h    = (const float*)d_in[0];
    const float* Wq   = (const float*)d_in[1];
    const float* Wk   = (const float*)d_in[2];
    const float* Wv   = (const float*)d_in[3];
    const float* cwq  = (const float*)d_in[4];
    const float* cwk  = (const float*)d_in[5];
    const float* cwv  = (const float*)d_in[6];
    const float* A_log= (const float*)d_in[7];
    const float* dtb  = (const float*)d_in[8];
    const float* Wfa  = (const float*)d_in[9];
    const float* Wfb  = (const float*)d_in[10];
    const float* Wb   = (const float*)d_in[11];
    const float* Wga  = (const float*)d_in[12];
    const float* Wgb  = (const float*)d_in[13];
    const float* nw   = (const float*)d_in[14];
    const float* Wo   = (const float*)d_in[15];
    float* out = (float*)d_out;   // reference output dtype is float32

    const int M = 4096, HID = 2048;
    const size_t big = (size_t)M * HID;
    float* ws    = (float*)d_ws;
    float* qb    = ws;
    float* kb    = qb + big;
    float* vb    = kb + big;
    float* gb    = vb + big;
    float* gateb = gb + big;
    float* ob    = gateb + big;
    float* tmpf  = ob + big;
    float* tmpg  = tmpf + (size_t)M * 128;
    float* betab = tmpg + (size_t)M * 128;

    dim3 blk(256);

    // 1) q/k/v projections (batched, shared A tiles through L2)
    gemm_tile<<<dim3(32, 16, 3), blk, 0, stream>>>(
        h, h, h, Wq, Wk, Wv, qb, kb, vb, M, HID, HID);

    // 2) low-rank stage 1: h@Wfa, h@Wga  (N=128)
    gemm_tile<<<dim3(32, 1, 2), blk, 0, stream>>>(
        h, h, h, Wfa, Wga, Wga, tmpf, tmpg, tmpg, M, 128, HID);

    // 3) low-rank stage 2: tmpf@Wfb -> gb, tmpg@Wgb -> gateb
    gemm_tile<<<dim3(32, 16, 2), blk, 0, stream>>>(
        tmpf, tmpg, tmpg, Wfb, Wgb, Wgb, gb, gateb, gateb, M, HID, 128);

    // 4) beta raw: h@Wb
    gemm_n16<<<dim3(M / 16), blk, 0, stream>>>(h, Wb, betab, M, HID);

    // 5) causal conv + SiLU (in-place on qb/kb/vb)
    conv_silu<<<dim3(48), blk, 0, stream>>>(qb, kb, vb, cwq, cwk, cwv);

    // 6) l2norm q/k, g -> exp(g) (in-place)
    prep_qkg<<<dim3(16384), blk, 0, stream>>>(qb, kb, gb, A_log, dtb, M * 16);

    // 7) gated delta-rule scan
    kda_scan<<<dim3(32), blk, 0, stream>>>(qb, kb, vb, gb, betab, ob);

    // 8) gated RMSNorm (in-place on ob)
    norm_gate<<<dim3(16384), blk, 0, stream>>>(ob, gateb, nw, M * 16);

    // 9) output projection -> f32
    gemm_tile<<<dim3(32, 16, 1), blk, 0, stream>>>(
        ob, ob, ob, Wo, Wo, Wo, out, out, out, M, HID, HID);
}